// Round 7
// baseline (60.925 us; speedup 1.0000x reference)
//
#include <hip/hip_runtime.h>
#include <math.h>

#define BB 1024   // batch (rows)
#define NN 64     // dims (cols)

#define LN2F 0.69314718055994530942f
#define BINS 256      // bins per unit interval
#define TW   64       // conv half-window in bins (3.27 sigma at h~0.0766)
#define HSIZE 769     // histogram bins over [-1,2]
#define NOUT 258      // output bins (abs bins 255..512)
#define OBASE 255

#define NBLOCKS 512

// Fused single kernel:
//   blocks [0,256):   KNN — 4 query rows each, per-wave selection
//   blocks [256,512): KDE — dim r = (bx-256)>>2, query chunk = (bx-256)&3
// Last-arriving block performs the final reduction and writes out[0..64].
__global__ __launch_bounds__(256, 4) void fused_kernel(const float* __restrict__ act,
                                                       const int* __restrict__ kptr,
                                                       float* __restrict__ logrho,
                                                       float* __restrict__ partial,
                                                       int* __restrict__ counter,
                                                       float* __restrict__ out,
                                                       double log_c_d, double dg_B) {
    const int bx = blockIdx.x;
    const int tid = threadIdx.x;

    __shared__ float s_d[4096];
    __shared__ float s_x[264];

    if (bx < 256) {
        // ---------------- KNN role: queries qbase..qbase+3 ----------------
        const int qbase = bx * 4;
        if (tid < 64) {
            ((float4*)s_x)[tid] = ((const float4*)(act + (size_t)qbase * NN))[tid];
        }
        __syncthreads();

        const float4* qf = (const float4*)s_x;
        float4 acc0 = {0,0,0,0}, acc1 = {0,0,0,0}, acc2 = {0,0,0,0}, acc3 = {0,0,0,0};
        const float4* row0 = (const float4*)(act + (size_t)(tid + 0)   * NN);
        const float4* row1 = (const float4*)(act + (size_t)(tid + 256) * NN);
        const float4* row2 = (const float4*)(act + (size_t)(tid + 512) * NN);
        const float4* row3 = (const float4*)(act + (size_t)(tid + 768) * NN);

        #pragma unroll 2
        for (int d = 0; d < 16; ++d) {
            const float4 q0 = qf[d];
            const float4 q1 = qf[16 + d];
            const float4 q2 = qf[32 + d];
            const float4 q3 = qf[48 + d];
            {   const float4 v = row0[d];
                float x,y,z,w;
                x=v.x-q0.x; y=v.y-q0.y; z=v.z-q0.z; w=v.w-q0.w; acc0.x += x*x+y*y+z*z+w*w;
                x=v.x-q1.x; y=v.y-q1.y; z=v.z-q1.z; w=v.w-q1.w; acc0.y += x*x+y*y+z*z+w*w;
                x=v.x-q2.x; y=v.y-q2.y; z=v.z-q2.z; w=v.w-q2.w; acc0.z += x*x+y*y+z*z+w*w;
                x=v.x-q3.x; y=v.y-q3.y; z=v.z-q3.z; w=v.w-q3.w; acc0.w += x*x+y*y+z*z+w*w; }
            {   const float4 v = row1[d];
                float x,y,z,w;
                x=v.x-q0.x; y=v.y-q0.y; z=v.z-q0.z; w=v.w-q0.w; acc1.x += x*x+y*y+z*z+w*w;
                x=v.x-q1.x; y=v.y-q1.y; z=v.z-q1.z; w=v.w-q1.w; acc1.y += x*x+y*y+z*z+w*w;
                x=v.x-q2.x; y=v.y-q2.y; z=v.z-q2.z; w=v.w-q2.w; acc1.z += x*x+y*y+z*z+w*w;
                x=v.x-q3.x; y=v.y-q3.y; z=v.z-q3.z; w=v.w-q3.w; acc1.w += x*x+y*y+z*z+w*w; }
            {   const float4 v = row2[d];
                float x,y,z,w;
                x=v.x-q0.x; y=v.y-q0.y; z=v.z-q0.z; w=v.w-q0.w; acc2.x += x*x+y*y+z*z+w*w;
                x=v.x-q1.x; y=v.y-q1.y; z=v.z-q1.z; w=v.w-q1.w; acc2.y += x*x+y*y+z*z+w*w;
                x=v.x-q2.x; y=v.y-q2.y; z=v.z-q2.z; w=v.w-q2.w; acc2.z += x*x+y*y+z*z+w*w;
                x=v.x-q3.x; y=v.y-q3.y; z=v.z-q3.z; w=v.w-q3.w; acc2.w += x*x+y*y+z*z+w*w; }
            {   const float4 v = row3[d];
                float x,y,z,w;
                x=v.x-q0.x; y=v.y-q0.y; z=v.z-q0.z; w=v.w-q0.w; acc3.x += x*x+y*y+z*z+w*w;
                x=v.x-q1.x; y=v.y-q1.y; z=v.z-q1.z; w=v.w-q1.w; acc3.y += x*x+y*y+z*z+w*w;
                x=v.x-q2.x; y=v.y-q2.y; z=v.z-q2.z; w=v.w-q2.w; acc3.z += x*x+y*y+z*z+w*w;
                x=v.x-q3.x; y=v.y-q3.y; z=v.z-q3.z; w=v.w-q3.w; acc3.w += x*x+y*y+z*z+w*w; }
        }
        s_d[0*1024 + tid +   0] = acc0.x;  s_d[1*1024 + tid +   0] = acc0.y;
        s_d[2*1024 + tid +   0] = acc0.z;  s_d[3*1024 + tid +   0] = acc0.w;
        s_d[0*1024 + tid + 256] = acc1.x;  s_d[1*1024 + tid + 256] = acc1.y;
        s_d[2*1024 + tid + 256] = acc1.z;  s_d[3*1024 + tid + 256] = acc1.w;
        s_d[0*1024 + tid + 512] = acc2.x;  s_d[1*1024 + tid + 512] = acc2.y;
        s_d[2*1024 + tid + 512] = acc2.z;  s_d[3*1024 + tid + 512] = acc2.w;
        s_d[0*1024 + tid + 768] = acc3.x;  s_d[1*1024 + tid + 768] = acc3.y;
        s_d[2*1024 + tid + 768] = acc3.z;  s_d[3*1024 + tid + 768] = acc3.w;
        __syncthreads();

        // wave w handles query qbase+w
        const int w = tid >> 6, lane = tid & 63;
        float v[16];
        #pragma unroll
        for (int c = 0; c < 16; ++c) v[c] = s_d[w * 1024 + lane + 64 * c];
        const int kk = kptr[0];
        float last = 0.f;
        for (int e = 0; e <= kk; ++e) {
            float bv = 1e30f; int bi = 0;
            #pragma unroll
            for (int c = 0; c < 16; ++c) { if (v[c] < bv) { bv = v[c]; bi = c; } }
            float mv = bv; int mi = (lane << 4) | bi;
            #pragma unroll
            for (int off = 32; off > 0; off >>= 1) {
                float ov = __shfl_xor(mv, off);
                int   oi = __shfl_xor(mi, off);
                if (ov < mv || (ov == mv && oi < mi)) { mv = ov; mi = oi; }
            }
            last = mv;
            if ((mi >> 4) == lane) v[mi & 15] = 1e30f;
        }
        if (lane == 0) {
            logrho[qbase + w] = __builtin_amdgcn_logf(fmaxf(last, 1e-12f)) * LN2F;
        }
    } else {
        // ---------------- KDE role: dim r, query chunk ----------------
        const int idx = bx - 256;
        const int r = idx >> 2;        // 0..63
        const int chunk = idx & 3;     // 0..3 (256 queries each)

        int*   hint = (int*)s_d;       // [0,769) histogram (int counts)
        float* harr = s_d;             // same storage as float after convert
        float* ktab = s_d + 772;       // 65 floats
        float* outg = s_d + 840;       // 258 floats

        float cv[4];
        float lsum = 0.f, lsq = 0.f;
        #pragma unroll
        for (int c = 0; c < 4; ++c) {
            const int j = tid + 256 * c;
            float v = act[(size_t)j * NN + r];
            cv[c] = v;
            lsum += v; lsq += v * v;
        }
        #pragma unroll
        for (int off = 32; off > 0; off >>= 1) {
            lsum += __shfl_xor(lsum, off);
            lsq  += __shfl_xor(lsq,  off);
        }
        const int wid = tid >> 6;
        if ((tid & 63) == 0) { s_x[wid] = lsum; s_x[4 + wid] = lsq; }

        for (int i = tid; i < HSIZE; i += 256) hint[i] = 0;
        __syncthreads();

        const float total = s_x[0] + s_x[1] + s_x[2] + s_x[3];
        const float totsq = s_x[4] + s_x[5] + s_x[6] + s_x[7];
        const float mean = total * (1.f / BB);
        const float var = (totsq - (float)BB * mean * mean) * (1.f / (BB - 1)); // ddof=1
        const float stdv = sqrtf(fmaxf(var, 0.f));
        const float h = fmaxf(1.06f * 0.25f * stdv, 1e-4f);   // 1024^-0.2 = 0.25
        const float ih = 1.f / h;
        const float a  = 0.84932180028801904272f * ih;        // sqrt(0.5*log2 e)/h
        const float ad = a * (1.f / (float)BINS);

        #pragma unroll
        for (int c = 0; c < 4; ++c) {
            const float x = cv[c];
            int b0 = (int)floorf(x * (float)BINS) + BINS;             // p = x
            int b1 = (int)floorf(-x * (float)BINS) + BINS;            // p = -x
            int b2 = (int)floorf((2.f - x) * (float)BINS) + BINS;     // p = 2-x
            b0 = min(max(b0, 0), HSIZE - 1);
            b1 = min(max(b1, 0), HSIZE - 1);
            b2 = min(max(b2, 0), HSIZE - 1);
            atomicAdd(&hint[b0], 1);
            atomicAdd(&hint[b1], 1);
            atomicAdd(&hint[b2], 1);
        }
        if (tid <= TW) {
            const float t = ad * (float)tid;
            ktab[tid] = __builtin_amdgcn_exp2f(-(t * t));
        }
        __syncthreads();

        for (int i = tid; i < HSIZE; i += 256) {
            const int c = hint[i];
            harr[i] = (float)c;
        }
        __syncthreads();

        for (int o = tid; o < NOUT; o += 256) {
            const float* hp = harr + OBASE + o;
            float acc = hp[0] * ktab[0];
            #pragma unroll 4
            for (int m = 1; m <= TW; ++m)
                acc += (hp[m] + hp[-m]) * ktab[m];
            outg[o] = acc;
        }
        __syncthreads();

        const float dscale = 0.39894228040143267794f * ih * (1.f / (float)BB);
        const float x = cv[chunk];
        const float u = fmaf(x, (float)BINS, (float)OBASE + 0.5f);
        const float fu = floorf(u);
        const int i0 = (int)fu - OBASE;
        const float f = u - fu;
        const float dv = outg[i0] + (outg[i0 + 1] - outg[i0]) * f;
        float lp = __builtin_amdgcn_logf(fmaf(dv, dscale, 1e-8f)) * LN2F;

        #pragma unroll
        for (int off = 32; off > 0; off >>= 1) lp += __shfl_xor(lp, off);
        if ((tid & 63) == 0) s_x[8 + wid] = lp;
        __syncthreads();
        if (tid == 0) {
            partial[idx] = s_x[8] + s_x[9] + s_x[10] + s_x[11];   // partial[r*4+chunk]
        }
    }

    // ---------------- arrival + last-block finalize ----------------
    __syncthreads();
    __threadfence();                       // release block's global writes (device scope)
    if (tid == 0) ((int*)s_x)[0] = atomicAdd(counter, 1);
    __syncthreads();
    if (((int*)s_x)[0] != NBLOCKS - 1) return;

    __threadfence();                       // acquire
    double* dred = (double*)s_d;           // 16 KB -> 2048 doubles available

    double s = 0.0;
    #pragma unroll
    for (int c = 0; c < 4; ++c)
        s += (double)atomicAdd(&logrho[tid + 256 * c], 0.0f);   // coherent read
    dred[tid] = s;
    __syncthreads();
    for (int st = 128; st > 0; st >>= 1) { if (tid < st) dred[tid] += dred[tid + st]; __syncthreads(); }

    if (tid == 0) {
        const int kk = kptr[0];
        double dgk = -0.57721566490153286061;                 // digamma(1)
        for (int t = 1; t < kk; ++t) dgk += 1.0 / (double)t;  // digamma(k)
        const double log_rho_sum = 0.5 * (dred[0] / (double)BB);
        const double h_nats = -dgk + dg_B + log_c_d + (double)NN * log_rho_sum;
        out[0] = (float)(h_nats / 0.69314718055994530942);
    }
    if (tid < NN) {
        float p = 0.f;
        #pragma unroll
        for (int c = 0; c < 4; ++c)
            p += atomicAdd(&partial[tid * 4 + c], 0.0f);        // coherent read
        out[1 + tid] = -p * (1.0f / (float)BB);
    }
}

extern "C" void kernel_launch(void* const* d_in, const int* in_sizes, int n_in,
                              void* d_out, int out_size, void* d_ws, size_t ws_size,
                              hipStream_t stream) {
    const float* act = (const float*)d_in[0];
    const int* kptr = (const int*)d_in[1];
    float* out = (float*)d_out;

    float* logrho  = (float*)d_ws;         // [0,1024) floats
    float* partial = logrho + BB;          // [1024,1280) floats
    int*   counter = (int*)(partial + 256);// 1 int at float-offset 1280

    const double log_c_d = 0.5 * (double)NN * log(M_PI) - lgamma((double)NN / 2.0 + 1.0);
    const double xB = (double)BB;          // digamma(1024) via asymptotic series
    const double dg_B = log(xB) - 1.0 / (2.0 * xB) - 1.0 / (12.0 * xB * xB)
                        + 1.0 / (120.0 * xB * xB * xB * xB);

    hipMemsetAsync(counter, 0, sizeof(int), stream);
    fused_kernel<<<NBLOCKS, 256, 0, stream>>>(act, kptr, logrho, partial, counter,
                                              out, log_c_d, dg_B);
}

// Round 10
// 30.059 us; speedup vs baseline: 2.0268x; 2.0268x over previous
//
#include <hip/hip_runtime.h>
#include <math.h>

#define BB 1024   // batch (rows)
#define NN 64     // dims (cols)

#define LN2F 0.69314718055994530942f
#define BINS 256      // bins per unit interval
#define TW   64       // conv half-window in bins (3.27 sigma at h~0.0766)
#define HSIZE 769     // histogram bins over [-1,2]
#define NOUT 258      // output bins (abs bins 255..512)
#define OBASE 255

#define NBLOCKS 512

// Fused single-dispatch kernel (+ 4-byte async memset of the arrival counter):
//   blocks [0,256):   KNN — 4 query rows each, per-wave selection
//   blocks [256,512): KDE — dim r = (bx-256)>>2, query chunk = (bx-256)&3
// Cross-block handoff: producers publish each slot with a RETURNING atomicExch
// (device-scope RMW completes at the coherence point before its vmcnt retires;
// __syncthreads' vmcnt(0) drain orders all publishes before the arrival RMW).
// Arrival counter is memset to 0 in-graph each launch, so `old == NBLOCKS-1`
// identifies the true last arriver on every replay (R8/R9's modular-counter
// scheme was wrong from nonzero starts). Last block reads slots back with
// atomicAdd(p, 0.0f) RMW-reads and writes out[0..64]. No __threadfence (R7's
// per-block L2-writeback stall).
__global__ __launch_bounds__(256, 4) void fused_kernel(const float* __restrict__ act,
                                                       const int* __restrict__ kptr,
                                                       float* __restrict__ logrho,
                                                       float* __restrict__ partial,
                                                       unsigned int* __restrict__ counter,
                                                       float* __restrict__ out,
                                                       double log_c_d, double dg_B) {
    const int bx = blockIdx.x;
    const int tid = threadIdx.x;

    __shared__ float s_d[4096];
    __shared__ float s_x[264];
    __shared__ int s_last;

    if (bx < 256) {
        // ---------------- KNN role: queries qbase..qbase+3 ----------------
        const int qbase = bx * 4;
        if (tid < 64) {
            ((float4*)s_x)[tid] = ((const float4*)(act + (size_t)qbase * NN))[tid];
        }
        __syncthreads();

        #pragma unroll 1
        for (int c = 0; c < 4; ++c) {
            const int j = tid + 256 * c;
            const float4* row = (const float4*)(act + (size_t)j * NN);
            float a0 = 0.f, a1 = 0.f, a2 = 0.f, a3 = 0.f;
            #pragma unroll 2
            for (int d = 0; d < 16; ++d) {
                const float4 v = row[d];
                {   const float4 qq = ((const float4*)s_x)[d];
                    float x0 = v.x - qq.x, x1 = v.y - qq.y, x2 = v.z - qq.z, x3 = v.w - qq.w;
                    a0 += x0 * x0 + x1 * x1 + x2 * x2 + x3 * x3; }
                {   const float4 qq = ((const float4*)s_x)[16 + d];
                    float x0 = v.x - qq.x, x1 = v.y - qq.y, x2 = v.z - qq.z, x3 = v.w - qq.w;
                    a1 += x0 * x0 + x1 * x1 + x2 * x2 + x3 * x3; }
                {   const float4 qq = ((const float4*)s_x)[32 + d];
                    float x0 = v.x - qq.x, x1 = v.y - qq.y, x2 = v.z - qq.z, x3 = v.w - qq.w;
                    a2 += x0 * x0 + x1 * x1 + x2 * x2 + x3 * x3; }
                {   const float4 qq = ((const float4*)s_x)[48 + d];
                    float x0 = v.x - qq.x, x1 = v.y - qq.y, x2 = v.z - qq.z, x3 = v.w - qq.w;
                    a3 += x0 * x0 + x1 * x1 + x2 * x2 + x3 * x3; }
            }
            s_d[0 * 1024 + j] = a0;
            s_d[1 * 1024 + j] = a1;
            s_d[2 * 1024 + j] = a2;
            s_d[3 * 1024 + j] = a3;
        }
        __syncthreads();

        // wave w handles query qbase+w
        const int w = tid >> 6, lane = tid & 63;
        float v[16];
        #pragma unroll
        for (int c = 0; c < 16; ++c) v[c] = s_d[w * 1024 + lane + 64 * c];
        const int kk = kptr[0];
        float last = 0.f;
        for (int e = 0; e <= kk; ++e) {
            float bv = 1e30f; int bi = 0;
            #pragma unroll
            for (int c = 0; c < 16; ++c) { if (v[c] < bv) { bv = v[c]; bi = c; } }
            float mv = bv; int mi = (lane << 4) | bi;
            #pragma unroll
            for (int off = 32; off > 0; off >>= 1) {
                float ov = __shfl_xor(mv, off);
                int   oi = __shfl_xor(mi, off);
                if (ov < mv || (ov == mv && oi < mi)) { mv = ov; mi = oi; }
            }
            last = mv;
            if ((mi >> 4) == lane) v[mi & 15] = 1e30f;
        }
        if (lane == 0) {
            const float lr = __builtin_amdgcn_logf(fmaxf(last, 1e-12f)) * LN2F;
            float old = atomicExch(&logrho[qbase + w], lr);   // publish at coherence point
            asm volatile("" :: "v"(old));
        }
    } else {
        // ---------------- KDE role: dim r, query chunk ----------------
        const int idx = bx - 256;
        const int r = idx >> 2;        // 0..63
        const int chunk = idx & 3;     // 0..3 (256 queries each)

        int*   hint = (int*)s_d;       // [0,769) histogram (int counts)
        float* harr = s_d;             // same storage as float after convert
        float* ktab = s_d + 772;       // 65 floats
        float* outg = s_d + 840;       // 258 floats

        float cv[4];
        float lsum = 0.f, lsq = 0.f;
        #pragma unroll
        for (int c = 0; c < 4; ++c) {
            const int j = tid + 256 * c;
            float v = act[(size_t)j * NN + r];
            cv[c] = v;
            lsum += v; lsq += v * v;
        }
        #pragma unroll
        for (int off = 32; off > 0; off >>= 1) {
            lsum += __shfl_xor(lsum, off);
            lsq  += __shfl_xor(lsq,  off);
        }
        const int wid = tid >> 6;
        if ((tid & 63) == 0) { s_x[wid] = lsum; s_x[4 + wid] = lsq; }

        for (int i = tid; i < HSIZE; i += 256) hint[i] = 0;
        __syncthreads();

        const float total = s_x[0] + s_x[1] + s_x[2] + s_x[3];
        const float totsq = s_x[4] + s_x[5] + s_x[6] + s_x[7];
        const float mean = total * (1.f / BB);
        const float var = (totsq - (float)BB * mean * mean) * (1.f / (BB - 1)); // ddof=1
        const float stdv = sqrtf(fmaxf(var, 0.f));
        const float h = fmaxf(1.06f * 0.25f * stdv, 1e-4f);   // 1024^-0.2 = 0.25
        const float ih = 1.f / h;
        const float a  = 0.84932180028801904272f * ih;        // sqrt(0.5*log2 e)/h
        const float ad = a * (1.f / (float)BINS);

        #pragma unroll
        for (int c = 0; c < 4; ++c) {
            const float x = cv[c];
            int b0 = (int)floorf(x * (float)BINS) + BINS;             // p = x
            int b1 = (int)floorf(-x * (float)BINS) + BINS;            // p = -x
            int b2 = (int)floorf((2.f - x) * (float)BINS) + BINS;     // p = 2-x
            b0 = min(max(b0, 0), HSIZE - 1);
            b1 = min(max(b1, 0), HSIZE - 1);
            b2 = min(max(b2, 0), HSIZE - 1);
            atomicAdd(&hint[b0], 1);
            atomicAdd(&hint[b1], 1);
            atomicAdd(&hint[b2], 1);
        }
        if (tid <= TW) {
            const float t = ad * (float)tid;
            ktab[tid] = __builtin_amdgcn_exp2f(-(t * t));
        }
        __syncthreads();

        for (int i = tid; i < HSIZE; i += 256) {
            const int c = hint[i];
            harr[i] = (float)c;
        }
        __syncthreads();

        for (int o = tid; o < NOUT; o += 256) {
            const float* hp = harr + OBASE + o;
            float acc = hp[0] * ktab[0];
            #pragma unroll 4
            for (int m = 1; m <= TW; ++m)
                acc += (hp[m] + hp[-m]) * ktab[m];
            outg[o] = acc;
        }
        __syncthreads();

        const float dscale = 0.39894228040143267794f * ih * (1.f / (float)BB);
        const float x = cv[chunk];
        const float u = fmaf(x, (float)BINS, (float)OBASE + 0.5f);
        const float fu = floorf(u);
        const int i0 = (int)fu - OBASE;
        const float f = u - fu;
        const float dv = outg[i0] + (outg[i0 + 1] - outg[i0]) * f;
        float lp = __builtin_amdgcn_logf(fmaf(dv, dscale, 1e-8f)) * LN2F;

        #pragma unroll
        for (int off = 32; off > 0; off >>= 1) lp += __shfl_xor(lp, off);
        if ((tid & 63) == 0) s_x[8 + wid] = lp;
        __syncthreads();
        if (tid == 0) {
            const float p = s_x[8] + s_x[9] + s_x[10] + s_x[11];   // partial[r*4+chunk]
            float old = atomicExch(&partial[idx], p);              // publish
            asm volatile("" :: "v"(old));
        }
    }

    // ---------------- arrival + last-block finalize ----------------
    // __syncthreads() drains each wave's vmcnt (returning atomics retire only
    // after completing at the coherence point) -> all publishes in this block
    // are globally visible before the arrival RMW below.
    __syncthreads();
    if (tid == 0) {
        asm volatile("s_waitcnt vmcnt(0)" ::: "memory");
        const unsigned int old = atomicAdd(counter, 1u);   // device-scope RMW
        s_last = (old == NBLOCKS - 1u);                    // counter memset to 0 in-graph
    }
    __syncthreads();
    if (!s_last) return;

    // consumer: RMW-reads execute at the coherence point -> always fresh
    double* dred = (double*)s_d;

    double s = 0.0;
    #pragma unroll
    for (int c = 0; c < 4; ++c)
        s += (double)atomicAdd(&logrho[tid + 256 * c], 0.0f);
    dred[tid] = s;
    __syncthreads();
    for (int st = 128; st > 0; st >>= 1) { if (tid < st) dred[tid] += dred[tid + st]; __syncthreads(); }

    if (tid == 0) {
        const int kk = kptr[0];
        double dgk = -0.57721566490153286061;                 // digamma(1)
        for (int t = 1; t < kk; ++t) dgk += 1.0 / (double)t;  // digamma(k)
        const double log_rho_sum = 0.5 * (dred[0] / (double)BB);
        const double h_nats = -dgk + dg_B + log_c_d + (double)NN * log_rho_sum;
        out[0] = (float)(h_nats / 0.69314718055994530942);
    }
    if (tid < NN) {
        float p = 0.f;
        #pragma unroll
        for (int c = 0; c < 4; ++c)
            p += atomicAdd(&partial[tid * 4 + c], 0.0f);
        out[1 + tid] = -p * (1.0f / (float)BB);
    }
}

extern "C" void kernel_launch(void* const* d_in, const int* in_sizes, int n_in,
                              void* d_out, int out_size, void* d_ws, size_t ws_size,
                              hipStream_t stream) {
    const float* act = (const float*)d_in[0];
    const int* kptr = (const int*)d_in[1];
    float* out = (float*)d_out;

    float* logrho  = (float*)d_ws;                  // [0,1024) floats
    float* partial = logrho + BB;                   // [1024,1280) floats
    unsigned int* counter = (unsigned int*)(partial + 256);  // 1 uint

    const double log_c_d = 0.5 * (double)NN * log(M_PI) - lgamma((double)NN / 2.0 + 1.0);
    const double xB = (double)BB;                   // digamma(1024) via asymptotic series
    const double dg_B = log(xB) - 1.0 / (2.0 * xB) - 1.0 / (12.0 * xB * xB)
                        + 1.0 / (120.0 * xB * xB * xB * xB);

    hipMemsetAsync(counter, 0, sizeof(unsigned int), stream);   // in-graph each replay
    fused_kernel<<<NBLOCKS, 256, 0, stream>>>(act, kptr, logrho, partial, counter,
                                              out, log_c_d, dg_B);
}

// Round 11
// 29.941 us; speedup vs baseline: 2.0348x; 1.0039x over previous
//
#include <hip/hip_runtime.h>
#include <math.h>

#define BB 1024   // batch (rows)
#define NN 64     // dims (cols)

#define LN2F 0.69314718055994530942f
#define BINS 256      // bins per unit interval
#define TW   64       // conv half-window in bins (3.27 sigma at h~0.0766)
#define HSIZE 769     // histogram bins over [-1,2]
#define NOUT 258      // output bins (abs bins 255..512)
#define OBASE 255

#define NBLOCKS 512
#define MAGIC 0x13579BDFu

// Single-node fused kernel (no memset, no second kernel):
//   blocks [0,256):   KNN — 4 query rows each, per-wave selection
//   blocks [256,512): KDE — dim r = (bx-256)>>2, query chunk = (bx-256)&3
// Publish: returning atomicExch per slot (device-scope RMW completes at the
// coherence point before vmcnt retires). Arrival: self-initializing counter —
// block 0 zeroes it (guarded by a MAGIC word, both RMW-accessed) on the first
// call after any poison/garbage state; all blocks RMW-poll MAGIC (steady state:
// single poll) before arriving. Last arriver finalizes from RMW-reads and
// resets the counter for the next call. Exact on every call from any initial
// d_ws state; steady-state drift is additionally safe because replay values
// are bitwise identical. No __threadfence (R7), no modular counter (R8/R9),
// no memset node (R10).
__global__ __launch_bounds__(256, 4) void fused_kernel(const float* __restrict__ act,
                                                       const int* __restrict__ kptr,
                                                       float* __restrict__ logrho,
                                                       float* __restrict__ partial,
                                                       unsigned int* __restrict__ counter,
                                                       unsigned int* __restrict__ magic,
                                                       float* __restrict__ out,
                                                       double log_c_d, double dg_B) {
    const int bx = blockIdx.x;
    const int tid = threadIdx.x;

    __shared__ float s_d[4096];
    __shared__ float s_x[264];
    __shared__ int s_last;

    if (bx < 256) {
        // ---------------- KNN role: queries qbase..qbase+3 ----------------
        const int qbase = bx * 4;
        if (tid < 64) {
            ((float4*)s_x)[tid] = ((const float4*)(act + (size_t)qbase * NN))[tid];
        }
        __syncthreads();

        #pragma unroll 1
        for (int c = 0; c < 4; ++c) {
            const int j = tid + 256 * c;
            const float4* row = (const float4*)(act + (size_t)j * NN);
            float a0 = 0.f, a1 = 0.f, a2 = 0.f, a3 = 0.f;
            #pragma unroll 2
            for (int d = 0; d < 16; ++d) {
                const float4 v = row[d];
                {   const float4 qq = ((const float4*)s_x)[d];
                    float x0 = v.x - qq.x, x1 = v.y - qq.y, x2 = v.z - qq.z, x3 = v.w - qq.w;
                    a0 += x0 * x0 + x1 * x1 + x2 * x2 + x3 * x3; }
                {   const float4 qq = ((const float4*)s_x)[16 + d];
                    float x0 = v.x - qq.x, x1 = v.y - qq.y, x2 = v.z - qq.z, x3 = v.w - qq.w;
                    a1 += x0 * x0 + x1 * x1 + x2 * x2 + x3 * x3; }
                {   const float4 qq = ((const float4*)s_x)[32 + d];
                    float x0 = v.x - qq.x, x1 = v.y - qq.y, x2 = v.z - qq.z, x3 = v.w - qq.w;
                    a2 += x0 * x0 + x1 * x1 + x2 * x2 + x3 * x3; }
                {   const float4 qq = ((const float4*)s_x)[48 + d];
                    float x0 = v.x - qq.x, x1 = v.y - qq.y, x2 = v.z - qq.z, x3 = v.w - qq.w;
                    a3 += x0 * x0 + x1 * x1 + x2 * x2 + x3 * x3; }
            }
            s_d[0 * 1024 + j] = a0;
            s_d[1 * 1024 + j] = a1;
            s_d[2 * 1024 + j] = a2;
            s_d[3 * 1024 + j] = a3;
        }
        __syncthreads();

        // wave w handles query qbase+w
        const int w = tid >> 6, lane = tid & 63;
        float v[16];
        #pragma unroll
        for (int c = 0; c < 16; ++c) v[c] = s_d[w * 1024 + lane + 64 * c];
        const int kk = kptr[0];
        float last = 0.f;
        for (int e = 0; e <= kk; ++e) {
            float bv = 1e30f; int bi = 0;
            #pragma unroll
            for (int c = 0; c < 16; ++c) { if (v[c] < bv) { bv = v[c]; bi = c; } }
            float mv = bv; int mi = (lane << 4) | bi;
            #pragma unroll
            for (int off = 32; off > 0; off >>= 1) {
                float ov = __shfl_xor(mv, off);
                int   oi = __shfl_xor(mi, off);
                if (ov < mv || (ov == mv && oi < mi)) { mv = ov; mi = oi; }
            }
            last = mv;
            if ((mi >> 4) == lane) v[mi & 15] = 1e30f;
        }
        if (lane == 0) {
            const float lr = __builtin_amdgcn_logf(fmaxf(last, 1e-12f)) * LN2F;
            float old = atomicExch(&logrho[qbase + w], lr);   // publish at coherence point
            asm volatile("" :: "v"(old));
        }
    } else {
        // ---------------- KDE role: dim r, query chunk ----------------
        const int idx = bx - 256;
        const int r = idx >> 2;        // 0..63
        const int chunk = idx & 3;     // 0..3 (256 queries each)

        int*   hint = (int*)s_d;       // [0,769) histogram (int counts)
        float* harr = s_d;             // same storage as float after convert
        float* ktab = s_d + 772;       // 65 floats
        float* outg = s_d + 840;       // 258 floats

        float cv[4];
        float lsum = 0.f, lsq = 0.f;
        #pragma unroll
        for (int c = 0; c < 4; ++c) {
            const int j = tid + 256 * c;
            float v = act[(size_t)j * NN + r];
            cv[c] = v;
            lsum += v; lsq += v * v;
        }
        #pragma unroll
        for (int off = 32; off > 0; off >>= 1) {
            lsum += __shfl_xor(lsum, off);
            lsq  += __shfl_xor(lsq,  off);
        }
        const int wid = tid >> 6;
        if ((tid & 63) == 0) { s_x[wid] = lsum; s_x[4 + wid] = lsq; }

        for (int i = tid; i < HSIZE; i += 256) hint[i] = 0;
        __syncthreads();

        const float total = s_x[0] + s_x[1] + s_x[2] + s_x[3];
        const float totsq = s_x[4] + s_x[5] + s_x[6] + s_x[7];
        const float mean = total * (1.f / BB);
        const float var = (totsq - (float)BB * mean * mean) * (1.f / (BB - 1)); // ddof=1
        const float stdv = sqrtf(fmaxf(var, 0.f));
        const float h = fmaxf(1.06f * 0.25f * stdv, 1e-4f);   // 1024^-0.2 = 0.25
        const float ih = 1.f / h;
        const float a  = 0.84932180028801904272f * ih;        // sqrt(0.5*log2 e)/h
        const float ad = a * (1.f / (float)BINS);

        #pragma unroll
        for (int c = 0; c < 4; ++c) {
            const float x = cv[c];
            int b0 = (int)floorf(x * (float)BINS) + BINS;             // p = x
            int b1 = (int)floorf(-x * (float)BINS) + BINS;            // p = -x
            int b2 = (int)floorf((2.f - x) * (float)BINS) + BINS;     // p = 2-x
            b0 = min(max(b0, 0), HSIZE - 1);
            b1 = min(max(b1, 0), HSIZE - 1);
            b2 = min(max(b2, 0), HSIZE - 1);
            atomicAdd(&hint[b0], 1);
            atomicAdd(&hint[b1], 1);
            atomicAdd(&hint[b2], 1);
        }
        if (tid <= TW) {
            const float t = ad * (float)tid;
            ktab[tid] = __builtin_amdgcn_exp2f(-(t * t));
        }
        __syncthreads();

        for (int i = tid; i < HSIZE; i += 256) {
            const int c = hint[i];
            harr[i] = (float)c;
        }
        __syncthreads();

        for (int o = tid; o < NOUT; o += 256) {
            const float* hp = harr + OBASE + o;
            float acc = hp[0] * ktab[0];
            #pragma unroll 4
            for (int m = 1; m <= TW; ++m)
                acc += (hp[m] + hp[-m]) * ktab[m];
            outg[o] = acc;
        }
        __syncthreads();

        const float dscale = 0.39894228040143267794f * ih * (1.f / (float)BB);
        const float x = cv[chunk];
        const float u = fmaf(x, (float)BINS, (float)OBASE + 0.5f);
        const float fu = floorf(u);
        const int i0 = (int)fu - OBASE;
        const float f = u - fu;
        const float dv = outg[i0] + (outg[i0 + 1] - outg[i0]) * f;
        float lp = __builtin_amdgcn_logf(fmaf(dv, dscale, 1e-8f)) * LN2F;

        #pragma unroll
        for (int off = 32; off > 0; off >>= 1) lp += __shfl_xor(lp, off);
        if ((tid & 63) == 0) s_x[8 + wid] = lp;
        __syncthreads();
        if (tid == 0) {
            const float p = s_x[8] + s_x[9] + s_x[10] + s_x[11];   // partial[r*4+chunk]
            float old = atomicExch(&partial[idx], p);              // publish
            asm volatile("" :: "v"(old));
        }
    }

    // ---------------- self-initializing arrival + last-block finalize ----------
    // __syncthreads() drains each wave's vmcnt (returning atomics retire only on
    // completion at the coherence point): all publishes precede the arrival RMW.
    __syncthreads();
    if (tid == 0) {
        asm volatile("s_waitcnt vmcnt(0)" ::: "memory");
        if (bx == 0) {
            // first call after garbage/poison: zero the counter, then open the gate
            if (atomicAdd(magic, 0u) != MAGIC) {
                unsigned int o1 = atomicExch(counter, 0u);
                asm volatile("" :: "v"(o1));
                asm volatile("s_waitcnt vmcnt(0)" ::: "memory");
                unsigned int o2 = atomicExch(magic, MAGIC);
                asm volatile("" :: "v"(o2));
            }
        }
        // gate: RMW-poll (steady state: first poll already MAGIC)
        while (atomicAdd(magic, 0u) != MAGIC) { __builtin_amdgcn_s_sleep(2); }
        const unsigned int old = atomicAdd(counter, 1u);   // device-scope RMW
        s_last = (old == NBLOCKS - 1u);
    }
    __syncthreads();
    if (!s_last) return;

    // consumer (true last arriver): RMW-reads at the coherence point -> fresh
    double* dred = (double*)s_d;

    double s = 0.0;
    #pragma unroll
    for (int c = 0; c < 4; ++c)
        s += (double)atomicAdd(&logrho[tid + 256 * c], 0.0f);
    dred[tid] = s;
    __syncthreads();
    for (int st = 128; st > 0; st >>= 1) { if (tid < st) dred[tid] += dred[tid + st]; __syncthreads(); }

    if (tid == 0) {
        const int kk = kptr[0];
        double dgk = -0.57721566490153286061;                 // digamma(1)
        for (int t = 1; t < kk; ++t) dgk += 1.0 / (double)t;  // digamma(k)
        const double log_rho_sum = 0.5 * (dred[0] / (double)BB);
        const double h_nats = -dgk + dg_B + log_c_d + (double)NN * log_rho_sum;
        out[0] = (float)(h_nats / 0.69314718055994530942);
    }
    if (tid < NN) {
        float p = 0.f;
        #pragma unroll
        for (int c = 0; c < 4; ++c)
            p += atomicAdd(&partial[tid * 4 + c], 0.0f);
        out[1 + tid] = -p * (1.0f / (float)BB);
    }
    __syncthreads();
    if (tid == 0) {
        unsigned int o = atomicExch(counter, 0u);   // reset for the next call
        asm volatile("" :: "v"(o));
    }
}

extern "C" void kernel_launch(void* const* d_in, const int* in_sizes, int n_in,
                              void* d_out, int out_size, void* d_ws, size_t ws_size,
                              hipStream_t stream) {
    const float* act = (const float*)d_in[0];
    const int* kptr = (const int*)d_in[1];
    float* out = (float*)d_out;

    float* logrho  = (float*)d_ws;                  // [0,1024) floats
    float* partial = logrho + BB;                   // [1024,1280) floats
    unsigned int* counter = (unsigned int*)(partial + 256);  // 1 uint
    unsigned int* magic   = counter + 1;                     // 1 uint

    const double log_c_d = 0.5 * (double)NN * log(M_PI) - lgamma((double)NN / 2.0 + 1.0);
    const double xB = (double)BB;                   // digamma(1024) via asymptotic series
    const double dg_B = log(xB) - 1.0 / (2.0 * xB) - 1.0 / (12.0 * xB * xB)
                        + 1.0 / (120.0 * xB * xB * xB * xB);

    fused_kernel<<<NBLOCKS, 256, 0, stream>>>(act, kptr, logrho, partial, counter,
                                              magic, out, log_c_d, dg_B);
}

// Round 12
// 23.183 us; speedup vs baseline: 2.6280x; 1.2915x over previous
//
#include <hip/hip_runtime.h>
#include <math.h>

#define BB 1024   // batch (rows)
#define NN 64     // dims (cols)

#define LN2F 0.69314718055994530942f
#define BINS 256      // bins per unit interval
#define TW   64       // conv half-window in bins (3.27 sigma at h~0.0766)
#define HSIZE 769     // histogram bins over [-1,2]
#define NOUT 258      // output bins (abs bins 255..512)
#define OBASE 255

// Fused kernel (two-dispatch structure, proven R6 skeleton):
//   blocks [0,256):   KNN — 4 query rows each; d-outer loop, q-frags in regs
//   blocks [256,512): KDE — dim r = (bx-256)>>2, query chunk = (bx-256)&3
__global__ __launch_bounds__(256, 4) void fused_kernel(const float* __restrict__ act,
                                                       const int* __restrict__ kptr,
                                                       float* __restrict__ logrho,
                                                       float* __restrict__ partial) {
    const int bx = blockIdx.x;
    const int tid = threadIdx.x;

    __shared__ float s_d[4096];
    __shared__ float s_x[264];

    if (bx < 256) {
        // ---------------- KNN role: queries qbase..qbase+3 ----------------
        const int qbase = bx * 4;
        if (tid < 64) {
            ((float4*)s_x)[tid] = ((const float4*)(act + (size_t)qbase * NN))[tid];
        }
        __syncthreads();

        const float4* qf = (const float4*)s_x;
        const float4* r0 = (const float4*)(act + (size_t)(tid +   0) * NN);
        const float4* r1 = (const float4*)(act + (size_t)(tid + 256) * NN);
        const float4* r2 = (const float4*)(act + (size_t)(tid + 512) * NN);
        const float4* r3 = (const float4*)(act + (size_t)(tid + 768) * NN);

        float a00=0.f,a01=0.f,a02=0.f,a03=0.f;   // row-group 0 vs queries 0..3
        float a10=0.f,a11=0.f,a12=0.f,a13=0.f;
        float a20=0.f,a21=0.f,a22=0.f,a23=0.f;
        float a30=0.f,a31=0.f,a32=0.f,a33=0.f;

        #pragma unroll 2
        for (int d = 0; d < 16; ++d) {
            const float4 q0 = qf[d];            // wave-uniform LDS reads (broadcast)
            const float4 q1 = qf[16 + d];
            const float4 q2 = qf[32 + d];
            const float4 q3 = qf[48 + d];
            const float4 v0 = r0[d];            // coalesced global (L2-resident)
            const float4 v1 = r1[d];
            const float4 v2 = r2[d];
            const float4 v3 = r3[d];
            float x,y,z,w;
            x=v0.x-q0.x; y=v0.y-q0.y; z=v0.z-q0.z; w=v0.w-q0.w; a00 += x*x+y*y+z*z+w*w;
            x=v0.x-q1.x; y=v0.y-q1.y; z=v0.z-q1.z; w=v0.w-q1.w; a01 += x*x+y*y+z*z+w*w;
            x=v0.x-q2.x; y=v0.y-q2.y; z=v0.z-q2.z; w=v0.w-q2.w; a02 += x*x+y*y+z*z+w*w;
            x=v0.x-q3.x; y=v0.y-q3.y; z=v0.z-q3.z; w=v0.w-q3.w; a03 += x*x+y*y+z*z+w*w;
            x=v1.x-q0.x; y=v1.y-q0.y; z=v1.z-q0.z; w=v1.w-q0.w; a10 += x*x+y*y+z*z+w*w;
            x=v1.x-q1.x; y=v1.y-q1.y; z=v1.z-q1.z; w=v1.w-q1.w; a11 += x*x+y*y+z*z+w*w;
            x=v1.x-q2.x; y=v1.y-q2.y; z=v1.z-q2.z; w=v1.w-q2.w; a12 += x*x+y*y+z*z+w*w;
            x=v1.x-q3.x; y=v1.y-q3.y; z=v1.z-q3.z; w=v1.w-q3.w; a13 += x*x+y*y+z*z+w*w;
            x=v2.x-q0.x; y=v2.y-q0.y; z=v2.z-q0.z; w=v2.w-q0.w; a20 += x*x+y*y+z*z+w*w;
            x=v2.x-q1.x; y=v2.y-q1.y; z=v2.z-q1.z; w=v2.w-q1.w; a21 += x*x+y*y+z*z+w*w;
            x=v2.x-q2.x; y=v2.y-q2.y; z=v2.z-q2.z; w=v2.w-q2.w; a22 += x*x+y*y+z*z+w*w;
            x=v2.x-q3.x; y=v2.y-q3.y; z=v2.z-q3.z; w=v2.w-q3.w; a23 += x*x+y*y+z*z+w*w;
            x=v3.x-q0.x; y=v3.y-q0.y; z=v3.z-q0.z; w=v3.w-q0.w; a30 += x*x+y*y+z*z+w*w;
            x=v3.x-q1.x; y=v3.y-q1.y; z=v3.z-q1.z; w=v3.w-q1.w; a31 += x*x+y*y+z*z+w*w;
            x=v3.x-q2.x; y=v3.y-q2.y; z=v3.z-q2.z; w=v3.w-q2.w; a32 += x*x+y*y+z*z+w*w;
            x=v3.x-q3.x; y=v3.y-q3.y; z=v3.z-q3.z; w=v3.w-q3.w; a33 += x*x+y*y+z*z+w*w;
        }
        s_d[0*1024 + tid +   0] = a00;  s_d[1*1024 + tid +   0] = a01;
        s_d[2*1024 + tid +   0] = a02;  s_d[3*1024 + tid +   0] = a03;
        s_d[0*1024 + tid + 256] = a10;  s_d[1*1024 + tid + 256] = a11;
        s_d[2*1024 + tid + 256] = a12;  s_d[3*1024 + tid + 256] = a13;
        s_d[0*1024 + tid + 512] = a20;  s_d[1*1024 + tid + 512] = a21;
        s_d[2*1024 + tid + 512] = a22;  s_d[3*1024 + tid + 512] = a23;
        s_d[0*1024 + tid + 768] = a30;  s_d[1*1024 + tid + 768] = a31;
        s_d[2*1024 + tid + 768] = a32;  s_d[3*1024 + tid + 768] = a33;
        __syncthreads();

        // wave w handles query qbase+w
        const int w = tid >> 6, lane = tid & 63;
        float v[16];
        #pragma unroll
        for (int c = 0; c < 16; ++c) v[c] = s_d[w * 1024 + lane + 64 * c];
        const int kk = kptr[0];
        float last = 0.f;
        for (int e = 0; e <= kk; ++e) {
            float bv = 1e30f; int bi = 0;
            #pragma unroll
            for (int c = 0; c < 16; ++c) { if (v[c] < bv) { bv = v[c]; bi = c; } }
            float mv = bv; int mi = (lane << 4) | bi;
            #pragma unroll
            for (int off = 32; off > 0; off >>= 1) {
                float ov = __shfl_xor(mv, off);
                int   oi = __shfl_xor(mi, off);
                if (ov < mv || (ov == mv && oi < mi)) { mv = ov; mi = oi; }
            }
            last = mv;
            if ((mi >> 4) == lane) v[mi & 15] = 1e30f;
        }
        if (lane == 0) {
            logrho[qbase + w] = __builtin_amdgcn_logf(fmaxf(last, 1e-12f)) * LN2F;
        }
    } else {
        // ---------------- KDE role: dim r, query chunk ----------------
        const int idx = bx - 256;
        const int r = idx >> 2;        // 0..63
        const int chunk = idx & 3;     // 0..3 (256 queries each)

        int*   hint = (int*)s_d;       // [0,769) histogram (int counts)
        float* harr = s_d;             // same storage as float after convert
        float* ktab = s_d + 772;       // 65 floats
        float* outg = s_d + 840;       // 258 floats

        float cv[4];
        float lsum = 0.f, lsq = 0.f;
        #pragma unroll
        for (int c = 0; c < 4; ++c) {
            const int j = tid + 256 * c;
            float v = act[(size_t)j * NN + r];
            cv[c] = v;
            lsum += v; lsq += v * v;
        }
        #pragma unroll
        for (int off = 32; off > 0; off >>= 1) {
            lsum += __shfl_xor(lsum, off);
            lsq  += __shfl_xor(lsq,  off);
        }
        const int wid = tid >> 6;
        if ((tid & 63) == 0) { s_x[wid] = lsum; s_x[4 + wid] = lsq; }

        for (int i = tid; i < HSIZE; i += 256) hint[i] = 0;
        __syncthreads();

        const float total = s_x[0] + s_x[1] + s_x[2] + s_x[3];
        const float totsq = s_x[4] + s_x[5] + s_x[6] + s_x[7];
        const float mean = total * (1.f / BB);
        const float var = (totsq - (float)BB * mean * mean) * (1.f / (BB - 1)); // ddof=1
        const float stdv = sqrtf(fmaxf(var, 0.f));
        const float h = fmaxf(1.06f * 0.25f * stdv, 1e-4f);   // 1024^-0.2 = 0.25
        const float ih = 1.f / h;
        const float a  = 0.84932180028801904272f * ih;        // sqrt(0.5*log2 e)/h
        const float ad = a * (1.f / (float)BINS);

        #pragma unroll
        for (int c = 0; c < 4; ++c) {
            const float x = cv[c];
            int b0 = (int)floorf(x * (float)BINS) + BINS;             // p = x
            int b1 = (int)floorf(-x * (float)BINS) + BINS;            // p = -x
            int b2 = (int)floorf((2.f - x) * (float)BINS) + BINS;     // p = 2-x
            b0 = min(max(b0, 0), HSIZE - 1);
            b1 = min(max(b1, 0), HSIZE - 1);
            b2 = min(max(b2, 0), HSIZE - 1);
            atomicAdd(&hint[b0], 1);
            atomicAdd(&hint[b1], 1);
            atomicAdd(&hint[b2], 1);
        }
        if (tid <= TW) {
            const float t = ad * (float)tid;
            ktab[tid] = __builtin_amdgcn_exp2f(-(t * t));
        }
        __syncthreads();

        for (int i = tid; i < HSIZE; i += 256) {
            const int c = hint[i];
            harr[i] = (float)c;
        }
        __syncthreads();

        for (int o = tid; o < NOUT; o += 256) {
            const float* hp = harr + OBASE + o;
            float acc = hp[0] * ktab[0];
            #pragma unroll 4
            for (int m = 1; m <= TW; ++m)
                acc += (hp[m] + hp[-m]) * ktab[m];
            outg[o] = acc;
        }
        __syncthreads();

        const float dscale = 0.39894228040143267794f * ih * (1.f / (float)BB);
        const float x = cv[chunk];
        const float u = fmaf(x, (float)BINS, (float)OBASE + 0.5f);
        const float fu = floorf(u);
        const int i0 = (int)fu - OBASE;
        const float f = u - fu;
        const float dv = outg[i0] + (outg[i0 + 1] - outg[i0]) * f;
        float lp = __builtin_amdgcn_logf(fmaf(dv, dscale, 1e-8f)) * LN2F;

        #pragma unroll
        for (int off = 32; off > 0; off >>= 1) lp += __shfl_xor(lp, off);
        if ((tid & 63) == 0) s_x[8 + wid] = lp;
        __syncthreads();
        if (tid == 0) {
            partial[idx] = s_x[8] + s_x[9] + s_x[10] + s_x[11];   // partial[r*4+chunk]
        }
    }
}

// ---------------- finalize: joint entropy scalar + 64 marginals ----------------
__global__ __launch_bounds__(256) void finalize_kernel(const float* __restrict__ logrho,
                                                       const float* __restrict__ partial,
                                                       const int* __restrict__ kptr,
                                                       double log_c_d, double dg_B,
                                                       float* __restrict__ out) {
    const int tid = threadIdx.x;
    __shared__ double red[256];

    double s = 0.0;
    #pragma unroll
    for (int c = 0; c < 4; ++c) s += (double)logrho[tid + 256 * c];
    red[tid] = s;
    __syncthreads();
    for (int st = 128; st > 0; st >>= 1) { if (tid < st) red[tid] += red[tid + st]; __syncthreads(); }

    if (tid == 0) {
        const int kk = kptr[0];
        double dgk = -0.57721566490153286061;                 // digamma(1)
        for (int t = 1; t < kk; ++t) dgk += 1.0 / (double)t;  // digamma(k)
        const double log_rho_sum = 0.5 * (red[0] / (double)BB);
        const double h_nats = -dgk + dg_B + log_c_d + (double)NN * log_rho_sum;
        out[0] = (float)(h_nats / 0.69314718055994530942);
    }
    if (tid < NN) {
        const float p = partial[tid * 4 + 0] + partial[tid * 4 + 1]
                      + partial[tid * 4 + 2] + partial[tid * 4 + 3];
        out[1 + tid] = -p * (1.0f / (float)BB);
    }
}

extern "C" void kernel_launch(void* const* d_in, const int* in_sizes, int n_in,
                              void* d_out, int out_size, void* d_ws, size_t ws_size,
                              hipStream_t stream) {
    const float* act = (const float*)d_in[0];
    const int* kptr = (const int*)d_in[1];
    float* out = (float*)d_out;

    float* logrho = (float*)d_ws;          // 1024 floats
    float* partial = logrho + BB;          // 256 floats (64 dims x 4 chunks)

    const double log_c_d = 0.5 * (double)NN * log(M_PI) - lgamma((double)NN / 2.0 + 1.0);
    const double xB = (double)BB;          // digamma(1024) via asymptotic series
    const double dg_B = log(xB) - 1.0 / (2.0 * xB) - 1.0 / (12.0 * xB * xB)
                        + 1.0 / (120.0 * xB * xB * xB * xB);

    fused_kernel<<<512, 256, 0, stream>>>(act, kptr, logrho, partial);
    finalize_kernel<<<1, 256, 0, stream>>>(logrho, partial, kptr, log_c_d, dg_B, out);
}